// Round 1
// baseline (322.381 us; speedup 1.0000x reference)
//
#include <hip/hip_runtime.h>
#include <hip/hip_bf16.h>
#include <stdint.h>

typedef short short8 __attribute__((ext_vector_type(8)));
typedef float f32x4 __attribute__((ext_vector_type(4)));

#define BATCH 16384
#define INF 1024
#define OUTF 1024
#define KD 8192   // 8 channels per input feature: x, T1..T7  (T0 folded into bias)

__device__ __forceinline__ unsigned short bfb(float f) {
    __hip_bfloat16 h = __float2bfloat16(f);
    return __builtin_bit_cast(unsigned short, h);
}

// Build W'[o, i*8+c] bf16: c==0 -> base_weight[o,i], c=1..7 -> C[o,i,c]
__global__ void prep_w(const float* __restrict__ C, const float* __restrict__ W,
                       unsigned short* __restrict__ Bw) {
    int g = blockIdx.x * 256 + threadIdx.x;   // 1M threads, one (o,i) feature each
    int o = g >> 10, i = g & 1023;
    const float* src = C + ((size_t)o * 8192 + i * 8);
    float4 v0 = *(const float4*)src;
    float4 v1 = *(const float4*)(src + 4);
    v0.x = W[o * 1024 + i];   // replace T0 slot with base weight
    short8 r;
    r[0] = bfb(v0.x); r[1] = bfb(v0.y); r[2] = bfb(v0.z); r[3] = bfb(v0.w);
    r[4] = bfb(v1.x); r[5] = bfb(v1.y); r[6] = bfb(v1.z); r[7] = bfb(v1.w);
    *(short8*)(Bw + (size_t)g * 8) = r;
}

// bias[o] = sum_i C[o,i,0]
__global__ void prep_bias(const float* __restrict__ C, float* __restrict__ bias) {
    int o = blockIdx.x;
    int tid = threadIdx.x;  // 256
    float s = 0.f;
    for (int i = tid; i < 1024; i += 256)
        s += C[(size_t)o * 8192 + (size_t)i * 8];
    #pragma unroll
    for (int off = 32; off > 0; off >>= 1) s += __shfl_down(s, off);
    __shared__ float red[4];
    if ((tid & 63) == 0) red[tid >> 6] = s;
    __syncthreads();
    if (tid == 0) bias[o] = red[0] + red[1] + red[2] + red[3];
}

// GEMM: M=16384, N=1024, K=8192. A computed on the fly (tanh + Chebyshev), B from ws.
__global__ __launch_bounds__(256, 2)
void cheby_gemm(const float* __restrict__ X, const unsigned short* __restrict__ Bw,
                const float* __restrict__ bias, float* __restrict__ Out) {
    // +8 bf16 pad per row (stride 144B) -> ds_read_b128 down to free 2-way conflict
    __shared__ unsigned short As[128][72];
    __shared__ unsigned short Bs[128][72];

    const int tid  = threadIdx.x;
    const int lane = tid & 63;
    const int wave = tid >> 6;
    const int wm = (wave >> 1) * 64;   // 2x2 wave grid, each wave 64x64 out
    const int wn = (wave & 1) * 64;

    const int bid = blockIdx.x;        // 128 m-tiles x 8 n-tiles
    const int m0 = (bid >> 3) * 128;
    const int n0 = (bid & 7) * 128;

    const int lr = lane & 15;          // fragment row/col
    const int lg = lane >> 4;          // k-group

    f32x4 acc[4][4] = {};

    for (int k0 = 0; k0 < KD; k0 += 64) {
        const int i0 = k0 >> 3;        // feature index base (8 features per K-step)
        __syncthreads();
        // ---- stage A: 128 rows x 8 features; compute x, tanh, T2..T7 ----
        #pragma unroll
        for (int j = 0; j < 4; ++j) {
            int p = tid + 256 * j;
            int row = p >> 3, f = p & 7;
            float xv = X[(size_t)(m0 + row) * INF + i0 + f];
            // tanh(x) = 1 - 2/(1+exp(2x)); exp via hw exp2, rcp via hw approx
            float e  = __builtin_amdgcn_exp2f(xv * 2.8853900817779268f); // 2*log2(e)
            float xn = 1.0f - 2.0f * __builtin_amdgcn_rcpf(1.0f + e);
            float x2 = xn + xn;
            float t2 = x2 * xn - 1.0f;
            float t3 = x2 * t2 - xn;
            float t4 = x2 * t3 - t2;
            float t5 = x2 * t4 - t3;
            float t6 = x2 * t5 - t4;
            float t7 = x2 * t6 - t5;
            short8 v;
            v[0] = bfb(xv); v[1] = bfb(xn); v[2] = bfb(t2); v[3] = bfb(t3);
            v[4] = bfb(t4); v[5] = bfb(t5); v[6] = bfb(t6); v[7] = bfb(t7);
            *(short8*)&As[row][f * 8] = v;
        }
        // ---- stage B: 128 n-rows x 64 k (bf16 from ws) ----
        #pragma unroll
        for (int j = 0; j < 4; ++j) {
            int p = tid + 256 * j;
            int r = p >> 3, c = p & 7;
            short8 v = *(const short8*)(Bw + (size_t)(n0 + r) * KD + k0 + c * 8);
            *(short8*)&Bs[r][c * 8] = v;
        }
        __syncthreads();
        // ---- compute: 2 k-subtiles x 4x4 fragments ----
        #pragma unroll
        for (int kk = 0; kk < 2; ++kk) {
            short8 af[4], bfr[4];
            #pragma unroll
            for (int mi = 0; mi < 4; ++mi)
                af[mi] = *(const short8*)&As[wm + mi * 16 + lr][kk * 32 + lg * 8];
            #pragma unroll
            for (int ni = 0; ni < 4; ++ni)
                bfr[ni] = *(const short8*)&Bs[wn + ni * 16 + lr][kk * 32 + lg * 8];
            #pragma unroll
            for (int mi = 0; mi < 4; ++mi) {
                #pragma unroll
                for (int ni = 0; ni < 4; ++ni) {
                    acc[mi][ni] = __builtin_amdgcn_mfma_f32_16x16x32_bf16(
                        af[mi], bfr[ni], acc[mi][ni], 0, 0, 0);
                }
            }
        }
    }

    // ---- epilogue: C/D layout col=lane&15, row=(lane>>4)*4+reg; add bias ----
    #pragma unroll
    for (int mi = 0; mi < 4; ++mi) {
        #pragma unroll
        for (int ni = 0; ni < 4; ++ni) {
            int col = n0 + wn + ni * 16 + lr;
            float bv = bias[col];
            #pragma unroll
            for (int r = 0; r < 4; ++r) {
                int row = m0 + wm + mi * 16 + lg * 4 + r;
                Out[(size_t)row * OUTF + col] = acc[mi][ni][r] + bv;
            }
        }
    }
}

extern "C" void kernel_launch(void* const* d_in, const int* in_sizes, int n_in,
                              void* d_out, int out_size, void* d_ws, size_t ws_size,
                              hipStream_t stream) {
    const float* x = (const float*)d_in[0];          // [16384,1024] f32
    const float* C = (const float*)d_in[1];          // [1024,1024,8] f32
    const float* W = (const float*)d_in[2];          // [1024,1024] f32
    float* out = (float*)d_out;                      // [16384,1024] f32

    unsigned short* Bw = (unsigned short*)d_ws;                          // 16 MB bf16 W'
    float* bias = (float*)((char*)d_ws + (size_t)16 * 1024 * 1024);      // 4 KB

    prep_w<<<4096, 256, 0, stream>>>(C, W, Bw);
    prep_bias<<<1024, 256, 0, stream>>>(C, bias);
    cheby_gemm<<<1024, 256, 0, stream>>>(x, Bw, bias, out);
}

// Round 2
// 263.152 us; speedup vs baseline: 1.2251x; 1.2251x over previous
//
#include <hip/hip_runtime.h>
#include <hip/hip_bf16.h>
#include <stdint.h>

typedef short short8 __attribute__((ext_vector_type(8)));
typedef float f32x4 __attribute__((ext_vector_type(4)));

#define KD 8192
#define NT 128   // K-tiles of 64

__device__ __forceinline__ unsigned short bfb(float f) {
    __hip_bfloat16 h = __float2bfloat16(f);
    return __builtin_bit_cast(unsigned short, h);
}

// Build W'[o, i*8+c] bf16: c==0 -> base_weight[o,i], c=1..7 -> C[o,i,c]
__global__ void prep_w(const float* __restrict__ C, const float* __restrict__ W,
                       unsigned short* __restrict__ Bw) {
    int g = blockIdx.x * 256 + threadIdx.x;
    int o = g >> 10, i = g & 1023;
    const float* src = C + ((size_t)o * 8192 + i * 8);
    float4 v0 = *(const float4*)src;
    float4 v1 = *(const float4*)(src + 4);
    v0.x = W[o * 1024 + i];
    short8 r;
    r[0] = bfb(v0.x); r[1] = bfb(v0.y); r[2] = bfb(v0.z); r[3] = bfb(v0.w);
    r[4] = bfb(v1.x); r[5] = bfb(v1.y); r[6] = bfb(v1.z); r[7] = bfb(v1.w);
    *(short8*)(Bw + (size_t)g * 8) = r;
}

// bias[o] = sum_i C[o,i,0]
__global__ void prep_bias(const float* __restrict__ C, float* __restrict__ bias) {
    int o = blockIdx.x;
    int tid = threadIdx.x;
    float s = 0.f;
    for (int i = tid; i < 1024; i += 256)
        s += C[(size_t)o * 8192 + (size_t)i * 8];
    #pragma unroll
    for (int off = 32; off > 0; off >>= 1) s += __shfl_down(s, off);
    __shared__ float red[4];
    if ((tid & 63) == 0) red[tid >> 6] = s;
    __syncthreads();
    if (tid == 0) bias[o] = red[0] + red[1] + red[2] + red[3];
}

// ---------------- 256x256x(K=64) 8-wave 4-phase pipelined GEMM ----------------

#define GLDS(NXT_, C_, TT_) \
    __builtin_amdgcn_global_load_lds( \
        (const __attribute__((address_space(1))) unsigned int*)((const char*)Bw + boff[C_] + (size_t)(TT_) * 128), \
        (__attribute__((address_space(3))) unsigned int*)(&Bs[NXT_][(wave * 4 + (C_)) * 8][0]), 16, 0, 0)

#define LDA8(DST_, CUR_, MI_, KK_) { \
    int row_ = wm + (MI_) * 16 + lr; \
    DST_ = *(const short8*)((const char*)&As[CUR_][0][0] + row_ * 128 + ((((KK_) * 4 + lg) ^ (row_ & 7)) * 16)); }

#define LDB8(DST_, CUR_, NI_, KK_) { \
    int row_ = wn + (NI_) * 16 + lr; \
    DST_ = *(const short8*)((const char*)&Bs[CUR_][0][0] + row_ * 128 + ((((KK_) * 4 + lg) ^ (row_ & 7)) * 16)); }

#define XLOAD(DST_, TI_) { \
    const float* ap_ = xbase + (size_t)(TI_) * 8; \
    asm volatile("global_load_dwordx4 %0, %1, off" : "=&v"(DST_) : "v"(ap_)); }

#define XFORM(NXT_, XV_) { \
    _Pragma("unroll") \
    for (int j_ = 0; j_ < 4; ++j_) { \
        float xv_ = XV_[j_]; \
        float e_  = __builtin_amdgcn_exp2f(xv_ * 2.8853900817779268f); \
        float xn_ = 1.0f - 2.0f * __builtin_amdgcn_rcpf(1.0f + e_); \
        float x2_ = xn_ + xn_; \
        float t2_ = x2_ * xn_ - 1.0f; \
        float t3_ = x2_ * t2_ - xn_; \
        float t4_ = x2_ * t3_ - t2_; \
        float t5_ = x2_ * t4_ - t3_; \
        float t6_ = x2_ * t5_ - t4_; \
        float t7_ = x2_ * t6_ - t5_; \
        short8 v_; \
        v_[0] = bfb(xv_); v_[1] = bfb(xn_); v_[2] = bfb(t2_); v_[3] = bfb(t3_); \
        v_[4] = bfb(t4_); v_[5] = bfb(t5_); v_[6] = bfb(t6_); v_[7] = bfb(t7_); \
        *(short8*)((char*)&As[NXT_][0][0] + woff[j_]) = v_; \
    } }

#define MFMA16(MB_) { \
    acc[MB_+0][0] = __builtin_amdgcn_mfma_f32_16x16x32_bf16(a0_, b0_, acc[MB_+0][0], 0, 0, 0); \
    acc[MB_+0][1] = __builtin_amdgcn_mfma_f32_16x16x32_bf16(a0_, b1_, acc[MB_+0][1], 0, 0, 0); \
    acc[MB_+0][2] = __builtin_amdgcn_mfma_f32_16x16x32_bf16(a0_, b2_, acc[MB_+0][2], 0, 0, 0); \
    acc[MB_+0][3] = __builtin_amdgcn_mfma_f32_16x16x32_bf16(a0_, b3_, acc[MB_+0][3], 0, 0, 0); \
    acc[MB_+1][0] = __builtin_amdgcn_mfma_f32_16x16x32_bf16(a1_, b0_, acc[MB_+1][0], 0, 0, 0); \
    acc[MB_+1][1] = __builtin_amdgcn_mfma_f32_16x16x32_bf16(a1_, b1_, acc[MB_+1][1], 0, 0, 0); \
    acc[MB_+1][2] = __builtin_amdgcn_mfma_f32_16x16x32_bf16(a1_, b2_, acc[MB_+1][2], 0, 0, 0); \
    acc[MB_+1][3] = __builtin_amdgcn_mfma_f32_16x16x32_bf16(a1_, b3_, acc[MB_+1][3], 0, 0, 0); \
    acc[MB_+2][0] = __builtin_amdgcn_mfma_f32_16x16x32_bf16(a2_, b0_, acc[MB_+2][0], 0, 0, 0); \
    acc[MB_+2][1] = __builtin_amdgcn_mfma_f32_16x16x32_bf16(a2_, b1_, acc[MB_+2][1], 0, 0, 0); \
    acc[MB_+2][2] = __builtin_amdgcn_mfma_f32_16x16x32_bf16(a2_, b2_, acc[MB_+2][2], 0, 0, 0); \
    acc[MB_+2][3] = __builtin_amdgcn_mfma_f32_16x16x32_bf16(a2_, b3_, acc[MB_+2][3], 0, 0, 0); \
    acc[MB_+3][0] = __builtin_amdgcn_mfma_f32_16x16x32_bf16(a3_, b0_, acc[MB_+3][0], 0, 0, 0); \
    acc[MB_+3][1] = __builtin_amdgcn_mfma_f32_16x16x32_bf16(a3_, b1_, acc[MB_+3][1], 0, 0, 0); \
    acc[MB_+3][2] = __builtin_amdgcn_mfma_f32_16x16x32_bf16(a3_, b2_, acc[MB_+3][2], 0, 0, 0); \
    acc[MB_+3][3] = __builtin_amdgcn_mfma_f32_16x16x32_bf16(a3_, b3_, acc[MB_+3][3], 0, 0, 0); }

#define TILE(CUR_, NXT_, T_, XC_, XD_) { \
    const int tn_ = ((T_) + 1 < NT) ? (T_) + 1 : NT - 1; \
    const int tl_ = ((T_) + 2 < NT) ? (T_) + 2 : NT - 1; \
    short8 a0_, a1_, a2_, a3_, b0_, b1_, b2_, b3_; \
    /* phase 0 */ \
    LDA8(a0_, CUR_, 0, 0) LDA8(a1_, CUR_, 1, 0) LDA8(a2_, CUR_, 2, 0) LDA8(a3_, CUR_, 3, 0) \
    LDB8(b0_, CUR_, 0, 0) LDB8(b1_, CUR_, 1, 0) LDB8(b2_, CUR_, 2, 0) LDB8(b3_, CUR_, 3, 0) \
    GLDS(NXT_, 0, tn_); GLDS(NXT_, 1, tn_); \
    __builtin_amdgcn_s_barrier(); \
    __builtin_amdgcn_s_setprio(1); \
    MFMA16(0) \
    __builtin_amdgcn_s_setprio(0); \
    __builtin_amdgcn_s_barrier(); \
    /* phase 1 */ \
    LDA8(a0_, CUR_, 4, 0) LDA8(a1_, CUR_, 5, 0) LDA8(a2_, CUR_, 6, 0) LDA8(a3_, CUR_, 7, 0) \
    GLDS(NXT_, 2, tn_); GLDS(NXT_, 3, tn_); \
    asm volatile("s_waitcnt vmcnt(4)" ::: "memory"); \
    __builtin_amdgcn_sched_barrier(0); \
    XFORM(NXT_, XC_) \
    __builtin_amdgcn_s_barrier(); \
    __builtin_amdgcn_s_setprio(1); \
    MFMA16(4) \
    __builtin_amdgcn_s_setprio(0); \
    __builtin_amdgcn_s_barrier(); \
    /* phase 2 */ \
    LDA8(a0_, CUR_, 0, 1) LDA8(a1_, CUR_, 1, 1) LDA8(a2_, CUR_, 2, 1) LDA8(a3_, CUR_, 3, 1) \
    LDB8(b0_, CUR_, 0, 1) LDB8(b1_, CUR_, 1, 1) LDB8(b2_, CUR_, 2, 1) LDB8(b3_, CUR_, 3, 1) \
    XLOAD(XD_, tl_) \
    __builtin_amdgcn_s_barrier(); \
    __builtin_amdgcn_s_setprio(1); \
    MFMA16(0) \
    __builtin_amdgcn_s_setprio(0); \
    __builtin_amdgcn_s_barrier(); \
    /* phase 3 */ \
    LDA8(a0_, CUR_, 4, 1) LDA8(a1_, CUR_, 5, 1) LDA8(a2_, CUR_, 6, 1) LDA8(a3_, CUR_, 7, 1) \
    __builtin_amdgcn_s_barrier(); \
    __builtin_amdgcn_s_setprio(1); \
    MFMA16(4) \
    __builtin_amdgcn_s_setprio(0); \
    asm volatile("s_waitcnt vmcnt(1) lgkmcnt(0)" ::: "memory"); \
    __builtin_amdgcn_sched_barrier(0); \
    __builtin_amdgcn_s_barrier(); \
    __builtin_amdgcn_sched_barrier(0); \
}

__global__ __launch_bounds__(512, 2)
void cheby_gemm(const float* __restrict__ X, const unsigned short* __restrict__ Bw,
                const float* __restrict__ bias, float* __restrict__ Out) {
    __shared__ unsigned short As[2][256][64];   // 64 KiB
    __shared__ unsigned short Bs[2][256][64];   // 64 KiB

    const int tid  = threadIdx.x;
    const int lane = tid & 63;
    const int wave = tid >> 6;

    // XCD-bijective swizzle: 256 blocks, 8 XCDs * 32; 2 XCDs share one n-tile
    int bid = blockIdx.x;
    int lin = (bid & 7) * 32 + (bid >> 3);
    const int m0 = (lin & 63) << 8;
    const int n0 = (lin >> 6) << 8;

    const int wm = (wave >> 2) * 128;   // 2 M-waves
    const int wn = (wave & 3) * 64;     // 4 N-waves
    const int lr = lane & 15;
    const int lg = lane >> 4;

    // A-transform mapping: thread -> (row, 4 features)
    const int arow = tid >> 1;
    const int af0  = (tid & 1) * 4;
    const float* xbase = X + (size_t)(m0 + arow) * 1024 + af0;
    unsigned int woff[4];
    #pragma unroll
    for (int j = 0; j < 4; ++j)
        woff[j] = (unsigned)(arow * 128 + (((af0 + j) ^ (arow & 7)) * 16));

    // B glds per-lane pre-swizzled source offsets (chunk ^= row&7)
    unsigned int boff[4];
    #pragma unroll
    for (int c = 0; c < 4; ++c) {
        int row   = (wave * 4 + c) * 8 + (lane >> 3);
        int chunk = (lane & 7) ^ (lane >> 3);
        boff[c] = ((unsigned)(n0 + row) * 8192u + (unsigned)chunk * 8u) * 2u;
    }

    f32x4 acc[8][4] = {};
    f32x4 xA, xB;

    // ---- prologue: stage tile 0 (B via glds, A via transform), x(0)/x(1) in flight ----
    GLDS(0, 0, 0); GLDS(0, 1, 0); GLDS(0, 2, 0); GLDS(0, 3, 0);
    XLOAD(xA, 0)
    XLOAD(xB, 1)
    asm volatile("s_waitcnt vmcnt(1)" ::: "memory");   // B(0)+x(0) done, x(1) in flight
    __builtin_amdgcn_sched_barrier(0);
    XFORM(0, xA)
    asm volatile("s_waitcnt lgkmcnt(0)" ::: "memory");
    __builtin_amdgcn_s_barrier();
    __builtin_amdgcn_sched_barrier(0);

    for (int t = 0; t < NT; t += 2) {
        TILE(0, 1, t,     xB, xA)
        TILE(1, 0, t + 1, xA, xB)
    }

    // ---- epilogue: C layout col=lane&15, row=(lane>>4)*4+reg; add bias ----
    #pragma unroll
    for (int ni = 0; ni < 4; ++ni) {
        int col = n0 + wn + ni * 16 + lr;
        float bv = bias[col];
        #pragma unroll
        for (int mi = 0; mi < 8; ++mi) {
            #pragma unroll
            for (int r = 0; r < 4; ++r) {
                int row = m0 + wm + mi * 16 + lg * 4 + r;
                Out[(size_t)row * 1024 + col] = acc[mi][ni][r] + bv;
            }
        }
    }
}

extern "C" void kernel_launch(void* const* d_in, const int* in_sizes, int n_in,
                              void* d_out, int out_size, void* d_ws, size_t ws_size,
                              hipStream_t stream) {
    const float* x = (const float*)d_in[0];          // [16384,1024] f32
    const float* C = (const float*)d_in[1];          // [1024,1024,8] f32
    const float* W = (const float*)d_in[2];          // [1024,1024] f32
    float* out = (float*)d_out;                      // [16384,1024] f32

    unsigned short* Bw = (unsigned short*)d_ws;                          // 16 MB bf16 W'
    float* bias = (float*)((char*)d_ws + (size_t)16 * 1024 * 1024);      // 4 KB

    prep_w<<<4096, 256, 0, stream>>>(C, W, Bw);
    prep_bias<<<1024, 256, 0, stream>>>(C, bias);
    cheby_gemm<<<256, 512, 0, stream>>>(x, Bw, bias, out);
}